// Round 1
// baseline (29.385 us; speedup 1.0000x reference)
//
#include <hip/hip_runtime.h>

// SubTrajectoryBalanceLoss:
//   residual[b,t] = log_z + suffix_pf[b,t] - log_R[b] - suffix_pb[b,t]
//   out = sum_t( lambda^(L-1-t) * mean_b(residual^2) ) / L
//
// Key fact: weight lambda^(L-1-t) underflows (f32) for L-1-t >~ 750 and is
// < 1e-46 (f64) beyond k=1024. Suffix sums only involve u >= t, so columns
// t < L-1024 influence ONLY zero-weight terms -> skip them exactly.
// Read traffic: 2 * B * 1024 * 4B = 33.6 MB instead of 134 MB.

constexpr float LAMBDA  = 0.9f;
constexpr int   K_COLS  = 1024;             // last K columns of each row
constexpr int   WAVES_PB = 4;               // one wave (64 lanes) per row
constexpr int   CH      = K_COLS / 64;      // 16 elements per lane

__global__ __launch_bounds__(256) void stb_rows_kernel(
    const float* __restrict__ pf,
    const float* __restrict__ pb,
    const float* __restrict__ lr,
    const float* __restrict__ lz,
    double* __restrict__ acc_out,
    int B, int L)
{
    const int wave = threadIdx.x >> 6;
    const int lane = threadIdx.x & 63;
    const int row  = blockIdx.x * WAVES_PB + wave;

    float acc = 0.f;
    if (row < B) {
        const float cb = lz[0] - lr[row];
        const long long base = (long long)row * L + (L - K_COLS);
        const float4* pf4 = reinterpret_cast<const float4*>(pf + base) + lane * (CH / 4);
        const float4* pb4 = reinterpret_cast<const float4*>(pb + base) + lane * (CH / 4);

        float d[CH];
        #pragma unroll
        for (int k = 0; k < CH / 4; ++k) {
            float4 a  = pf4[k];
            float4 b4 = pb4[k];
            d[4*k+0] = a.x - b4.x;
            d[4*k+1] = a.y - b4.y;
            d[4*k+2] = a.z - b4.z;
            d[4*k+3] = a.w - b4.w;
        }
        float localSum = 0.f;
        #pragma unroll
        for (int j = 0; j < CH; ++j) localSum += d[j];

        // wave-wide inclusive suffix scan of localSum (no LDS, no barriers)
        float s = localSum;
        #pragma unroll
        for (int off = 1; off < 64; off <<= 1) {
            float v = __shfl_down(s, off);
            if (lane + off > 63) v = 0.f;
            s += v;
        }
        float run = s - localSum;   // sum of chunks strictly after mine

        // t_global = (L-K_COLS) + lane*CH + j ; exponent = K_COLS-1 - (lane*CH + j)
        // start at j = CH-1 -> exponent K_COLS - CH - lane*CH
        float w = powf(LAMBDA, (float)(K_COLS - CH - lane * CH));
        #pragma unroll
        for (int j = CH - 1; j >= 0; --j) {
            run += d[j];
            float r = cb + run;
            acc = fmaf(w * r, r, acc);
            w *= LAMBDA;            // moving t -> t-1 raises exponent by 1
        }
    }

    // wave reduce
    #pragma unroll
    for (int off = 32; off > 0; off >>= 1) acc += __shfl_down(acc, off);

    __shared__ double wacc[WAVES_PB];
    if (lane == 0) wacc[wave] = (double)acc;
    __syncthreads();
    if (threadIdx.x == 0) {
        double tot = 0.0;
        #pragma unroll
        for (int wv = 0; wv < WAVES_PB; ++wv) tot += wacc[wv];
        atomicAdd(acc_out, tot);
    }
}

// Generic (slow, always-correct) fallback: one thread per row, full-row scan.
__global__ void stb_generic_kernel(
    const float* __restrict__ pf,
    const float* __restrict__ pb,
    const float* __restrict__ lr,
    const float* __restrict__ lz,
    double* __restrict__ acc_out,
    int B, int L)
{
    int row = blockIdx.x * blockDim.x + threadIdx.x;
    if (row >= B) return;
    const float cb = lz[0] - lr[row];
    const long long base = (long long)row * L;
    float run = 0.f, w = 1.0f;
    double acc = 0.0;
    for (int t = L - 1; t >= 0; --t) {
        run += pf[base + t] - pb[base + t];
        float r = cb + run;
        acc += (double)(w * r * r);
        w *= LAMBDA;
    }
    atomicAdd(acc_out, acc);
}

__global__ void stb_finalize(const double* __restrict__ acc,
                             float* __restrict__ out, double invBL)
{
    out[0] = (float)(acc[0] * invBL);
}

extern "C" void kernel_launch(void* const* d_in, const int* in_sizes, int n_in,
                              void* d_out, int out_size, void* d_ws, size_t ws_size,
                              hipStream_t stream) {
    const float* pf = (const float*)d_in[0];
    const float* pb = (const float*)d_in[1];
    const float* lr = (const float*)d_in[2];
    const float* lz = (const float*)d_in[3];
    const int B = in_sizes[2];
    const int L = in_sizes[0] / B;

    double* acc = (double*)d_ws;
    hipMemsetAsync(acc, 0, sizeof(double), stream);

    if (L >= K_COLS && (L % 4) == 0 && ((L - K_COLS) % 4) == 0) {
        int grid = (B + WAVES_PB - 1) / WAVES_PB;
        stb_rows_kernel<<<grid, 256, 0, stream>>>(pf, pb, lr, lz, acc, B, L);
    } else {
        int grid = (B + 255) / 256;
        stb_generic_kernel<<<grid, 256, 0, stream>>>(pf, pb, lr, lz, acc, B, L);
    }

    stb_finalize<<<1, 1, 0, stream>>>(acc, (float*)d_out,
                                      1.0 / ((double)B * (double)L));
}

// Round 2
// 12.294 us; speedup vs baseline: 2.3902x; 2.3902x over previous
//
#include <hip/hip_runtime.h>

// SubTrajectoryBalanceLoss:
//   residual[b,t] = log_z + suffix_pf[b,t] - log_R[b] - suffix_pb[b,t]
//   out = sum_t( lambda^(L-1-t) * mean_b(residual^2) ) / L
//
// Weight lambda^(L-1-t) < 1e-46 beyond k=1024 (underflows even f64 math in
// the reference's f32 weights far earlier: f32 underflow at k~750, and the
// contribution bound lambda^1024 * max(r^2) is astronomically below the
// absmax threshold). Suffix sums only involve u >= t, so columns
// t < L-1024 influence ONLY zero-weight terms -> skip them exactly.
// Read traffic: 2 * B * 1024 * 4B = 33.6 MB instead of 134 MB.
//
// Structure (2 dispatches, no memset, no atomics):
//   stb_rows_kernel: 1 wave per row, per-block double partial -> ws (overwrite)
//   stb_reduce:      1 block reduces partials, scales, writes d_out[0]

constexpr float LAMBDA   = 0.9f;
constexpr int   K_COLS   = 1024;            // last K columns of each row
constexpr int   WAVES_PB = 4;               // waves (rows) per block
constexpr int   CH       = K_COLS / 64;     // 16 elements per lane

__global__ __launch_bounds__(256) void stb_rows_kernel(
    const float* __restrict__ pf,
    const float* __restrict__ pb,
    const float* __restrict__ lr,
    const float* __restrict__ lz,
    double* __restrict__ partials,
    int B, int L)
{
    const int wave = threadIdx.x >> 6;
    const int lane = threadIdx.x & 63;
    const int row  = blockIdx.x * WAVES_PB + wave;

    float acc = 0.f;
    if (row < B) {
        const float cb = lz[0] - lr[row];
        const long long base = (long long)row * L + (L - K_COLS);
        const float4* pf4 = reinterpret_cast<const float4*>(pf + base) + lane * (CH / 4);
        const float4* pb4 = reinterpret_cast<const float4*>(pb + base) + lane * (CH / 4);

        float d[CH];
        #pragma unroll
        for (int k = 0; k < CH / 4; ++k) {
            float4 a  = pf4[k];
            float4 b4 = pb4[k];
            d[4*k+0] = a.x - b4.x;
            d[4*k+1] = a.y - b4.y;
            d[4*k+2] = a.z - b4.z;
            d[4*k+3] = a.w - b4.w;
        }
        float localSum = 0.f;
        #pragma unroll
        for (int j = 0; j < CH; ++j) localSum += d[j];

        // wave-wide suffix scan of chunk sums (no LDS, no barriers)
        float s = localSum;
        #pragma unroll
        for (int off = 1; off < 64; off <<= 1) {
            float v = __shfl_down(s, off);
            if (lane + off > 63) v = 0.f;
            s += v;
        }
        float run = s - localSum;   // sum of chunks strictly after mine

        // exponent at j=CH-1 is K_COLS - CH - lane*CH; each j-- multiplies by lambda
        float w = powf(LAMBDA, (float)(K_COLS - CH - lane * CH));
        #pragma unroll
        for (int j = CH - 1; j >= 0; --j) {
            run += d[j];
            float r = cb + run;
            acc = fmaf(w * r, r, acc);
            w *= LAMBDA;
        }
    }

    // wave reduce (f32 partial per wave is ~<1e3; fine in f32)
    #pragma unroll
    for (int off = 32; off > 0; off >>= 1) acc += __shfl_down(acc, off);

    __shared__ float wacc[WAVES_PB];
    if (lane == 0) wacc[wave] = acc;
    __syncthreads();
    if (threadIdx.x == 0) {
        double tot = 0.0;
        #pragma unroll
        for (int wv = 0; wv < WAVES_PB; ++wv) tot += (double)wacc[wv];
        partials[blockIdx.x] = tot;      // pure overwrite: no init needed
    }
}

// Generic (slow, always-correct) fallback: one thread per row, full-row scan.
__global__ void stb_generic_kernel(
    const float* __restrict__ pf,
    const float* __restrict__ pb,
    const float* __restrict__ lr,
    const float* __restrict__ lz,
    double* __restrict__ partials,
    int B, int L)
{
    int row = blockIdx.x * blockDim.x + threadIdx.x;
    double acc = 0.0;
    if (row < B) {
        const float cb = lz[0] - lr[row];
        const long long base = (long long)row * L;
        float run = 0.f, w = 1.0f;
        for (int t = L - 1; t >= 0; --t) {
            run += pf[base + t] - pb[base + t];
            float r = cb + run;
            acc += (double)(w * r * r);
            w *= LAMBDA;
        }
    }
    // block reduce via LDS
    __shared__ double sacc[256];
    sacc[threadIdx.x] = acc;
    __syncthreads();
    for (int s = 128; s > 0; s >>= 1) {
        if (threadIdx.x < s) sacc[threadIdx.x] += sacc[threadIdx.x + s];
        __syncthreads();
    }
    if (threadIdx.x == 0) partials[blockIdx.x] = sacc[0];
}

__global__ __launch_bounds__(256) void stb_reduce(
    const double* __restrict__ partials, int n,
    float* __restrict__ out, double invBL)
{
    double acc = 0.0;
    for (int i = threadIdx.x; i < n; i += 256) acc += partials[i];
    #pragma unroll
    for (int off = 32; off > 0; off >>= 1) acc += __shfl_down(acc, off);
    __shared__ double wacc[4];
    int wave = threadIdx.x >> 6, lane = threadIdx.x & 63;
    if (lane == 0) wacc[wave] = acc;
    __syncthreads();
    if (threadIdx.x == 0) {
        double tot = wacc[0] + wacc[1] + wacc[2] + wacc[3];
        out[0] = (float)(tot * invBL);
    }
}

extern "C" void kernel_launch(void* const* d_in, const int* in_sizes, int n_in,
                              void* d_out, int out_size, void* d_ws, size_t ws_size,
                              hipStream_t stream) {
    const float* pf = (const float*)d_in[0];
    const float* pb = (const float*)d_in[1];
    const float* lr = (const float*)d_in[2];
    const float* lz = (const float*)d_in[3];
    const int B = in_sizes[2];
    const int L = in_sizes[0] / B;

    double* partials = (double*)d_ws;
    int nPartials;

    if (L >= K_COLS && ((L - K_COLS) % 4) == 0) {
        nPartials = (B + WAVES_PB - 1) / WAVES_PB;
        stb_rows_kernel<<<nPartials, 256, 0, stream>>>(pf, pb, lr, lz,
                                                       partials, B, L);
    } else {
        nPartials = (B + 255) / 256;
        stb_generic_kernel<<<nPartials, 256, 0, stream>>>(pf, pb, lr, lz,
                                                          partials, B, L);
    }

    stb_reduce<<<1, 256, 0, stream>>>(partials, nPartials, (float*)d_out,
                                      1.0 / ((double)B * (double)L));
}